// Round 1
// 206.391 us; speedup vs baseline: 1.1374x; 1.1374x over previous
//
#include <hip/hip_runtime.h>
#include <math.h>

#define THREADS 256   // 8 threads per token; thread = one expert group
#define TPB 32        // tokens per block
#define NEXP 256
#define EPS_S 2.0e-6f // single-score margins (f32 score err <= ~4e-7, 5x safety)
#define EPS_G 4.0e-6f // group-sum margins

// ---- fast f32 sigmoid: hw v_exp_f32 + fast divide ----
__device__ __forceinline__ float fsigmoid(float x) {
    float e = __expf(-x);
    return __fdividef(1.0f, 1.0f + e);
}

// ---- cheap near-exact f64 sigmoid (rare paths only): Taylor exp + NR division ----
__device__ __forceinline__ double dsigmoid(float xf) {
    xf = fminf(fmaxf(xf, -500.0f), 500.0f);
    double x = (double)xf;
    double t = x * -1.4426950408889634074;           // -x*log2(e)
    double n = floor(t + 0.5);
    int ni = (int)n;
    double u = (t - n) * 0.69314718055994530942;
    double pp = 2.08767569878680990e-9;
    pp = fma(pp, u, 2.50521083854417188e-8);
    pp = fma(pp, u, 2.75573192239858907e-7);
    pp = fma(pp, u, 2.75573192239858883e-6);
    pp = fma(pp, u, 2.48015873015873016e-5);
    pp = fma(pp, u, 1.98412698412698413e-4);
    pp = fma(pp, u, 1.38888888888888889e-3);
    pp = fma(pp, u, 8.33333333333333333e-3);
    pp = fma(pp, u, 4.16666666666666667e-2);
    pp = fma(pp, u, 1.66666666666666667e-1);
    pp = fma(pp, u, 0.5);
    pp = fma(pp, u, 1.0);
    pp = fma(pp, u, 1.0);
    double sc = __longlong_as_double((long long)(1023 + ni) << 52);
    double e = pp * sc;                              // exp(-x)
    double w = 1.0 + e;
    double y = (double)__fdividef(1.0f, (float)w);
    y = fma(y, fma(-w, y, 1.0), y);
    y = fma(y, fma(-w, y, 1.0), y);
    return y;
}

// 9-deep sorted-descending insert (named scalars m0..m8 / n0..n8), gated on m8.
// strict > : existing (earlier/lower-id) entry wins ties.
#define MINS(cc, ee) do {                                                \
    float _c=(cc); int _e=(ee);                                          \
    if (_c > m8) {                                                       \
        bool _b0=_c>m0,_b1=_c>m1,_b2=_c>m2,_b3=_c>m3,_b4=_c>m4,          \
             _b5=_c>m5,_b6=_c>m6,_b7=_c>m7;                              \
        m8=_b7?m7:_c;           n8=_b7?n7:_e;                            \
        m7=_b6?m6:(_b7?_c:m7);  n7=_b6?n6:(_b7?_e:n7);                   \
        m6=_b5?m5:(_b6?_c:m6);  n6=_b5?n5:(_b6?_e:n6);                   \
        m5=_b4?m4:(_b5?_c:m5);  n5=_b4?n4:(_b5?_e:n5);                   \
        m4=_b3?m3:(_b4?_c:m4);  n4=_b3?n3:(_b4?_e:n4);                   \
        m3=_b2?m2:(_b3?_c:m3);  n3=_b2?n2:(_b3?_e:n3);                   \
        m2=_b1?m1:(_b2?_c:m2);  n2=_b1?n1:(_b2?_e:n2);                   \
        m1=_b0?m0:(_b1?_c:m1);  n1=_b0?n0:(_b1?_e:n1);                   \
        m0=_b0?_c:m0;           n0=_b0?_e:n0;                            \
    } } while (0)

// f64 8-deep sorted insert (cold path)
#define DINS(cc, ee) do {                                                \
    double _d=(cc); int _e=(ee);                                         \
    if (_d > s7) {                                                       \
        bool _b0=_d>s0,_b1=_d>s1,_b2=_d>s2,_b3=_d>s3,_b4=_d>s4,          \
             _b5=_d>s5,_b6=_d>s6;                                        \
        s7=_b6?s6:_d;           c7=_b6?c6:_e;                            \
        s6=_b5?s5:(_b6?_d:s6);  c6=_b5?c5:(_b6?_e:c6);                   \
        s5=_b4?s4:(_b5?_d:s5);  c5=_b4?c4:(_b5?_e:c5);                   \
        s4=_b3?s3:(_b4?_d:s4);  c4=_b3?c3:(_b4?_e:c4);                   \
        s3=_b2?s2:(_b3?_d:s3);  c3=_b2?c2:(_b3?_e:c3);                   \
        s2=_b1?s1:(_b2?_d:s2);  c2=_b1?c1:(_b2?_e:c2);                   \
        s1=_b0?s0:(_b1?_d:s1);  c1=_b0?c0:(_b1?_e:c1);                   \
        s0=_b0?_d:s0;           c0=_b0?_e:c0;                            \
    } } while (0)

// ---- total-order helpers: value desc, id asc on exact value ties ----
// TOMAX: a := max_TO(a, b)
#define TOMAX(av, ai, bv, bi) do {                                       \
    bool _g = ((bv) > (av)) || (((bv) == (av)) && ((bi) < (ai)));        \
    (av) = _g ? (bv) : (av); (ai) = _g ? (bi) : (ai);                    \
} while (0)

// TOCE: descending compare-exchange; a gets the TO-larger, b the smaller
#define TOCE(av, ai, bv, bi) do {                                        \
    bool _s = ((bv) > (av)) || (((bv) == (av)) && ((bi) < (ai)));        \
    float _tv = (av); int _ti = (ai);                                    \
    (av) = _s ? (bv) : (av); (ai) = _s ? (bi) : (ai);                    \
    (bv) = _s ? _tv : (bv); (bi) = _s ? _ti : (bi);                      \
} while (0)

// Merge my sorted-desc 9-list with xor-partner's via the bitonic identity:
//   t[i] = max(a[i], b[8-i]) is the top-9 multiset, as a "valley" sequence.
// Cleanup = 13-CE bitonic network (valley -> sorted desc), verified on
// valley-min at middle / both ends / pure inc / pure dec.
#define XMERGE_B(d) do {                                                 \
    float q0=__shfl_xor(m0,d,64), q1=__shfl_xor(m1,d,64),                \
          q2=__shfl_xor(m2,d,64), q3=__shfl_xor(m3,d,64),                \
          q4=__shfl_xor(m4,d,64), q5=__shfl_xor(m5,d,64),                \
          q6=__shfl_xor(m6,d,64), q7=__shfl_xor(m7,d,64),                \
          q8=__shfl_xor(m8,d,64);                                        \
    int   r0=__shfl_xor(n0,d,64), r1=__shfl_xor(n1,d,64),                \
          r2=__shfl_xor(n2,d,64), r3=__shfl_xor(n3,d,64),                \
          r4=__shfl_xor(n4,d,64), r5=__shfl_xor(n5,d,64),                \
          r6=__shfl_xor(n6,d,64), r7=__shfl_xor(n7,d,64),                \
          r8=__shfl_xor(n8,d,64);                                        \
    TOMAX(m0,n0,q8,r8); TOMAX(m1,n1,q7,r7); TOMAX(m2,n2,q6,r6);          \
    TOMAX(m3,n3,q5,r5); TOMAX(m4,n4,q4,r4); TOMAX(m5,n5,q3,r3);          \
    TOMAX(m6,n6,q2,r2); TOMAX(m7,n7,q1,r1); TOMAX(m8,n8,q0,r0);          \
    TOCE(m0,n0,m8,n8);                                                   \
    TOCE(m1,n1,m5,n5); TOCE(m2,n2,m6,n6); TOCE(m3,n3,m7,n7); TOCE(m4,n4,m8,n8); \
    TOCE(m1,n1,m3,n3); TOCE(m2,n2,m4,n4); TOCE(m5,n5,m7,n7); TOCE(m6,n6,m8,n8); \
    TOCE(m1,n1,m2,n2); TOCE(m3,n3,m4,n4); TOCE(m5,n5,m6,n6); TOCE(m7,n7,m8,n8); \
} while (0)

__device__ __forceinline__ float4 shfl4(float4 v, int src) {
    float4 r;
    r.x = __shfl(v.x, src, 64);
    r.y = __shfl(v.y, src, 64);
    r.z = __shfl(v.z, src, 64);
    r.w = __shfl(v.w, src, 64);
    return r;
}

__global__ __launch_bounds__(THREADS, 6)
void noauxtc_router_kernel(const float* __restrict__ logits,
                           const float* __restrict__ bias,
                           float* __restrict__ out,   // [T*8] weights, [T*8] ids-as-f32
                           int T)
{
    __shared__ __align__(16) float bias_sh[NEXP];      // 1 KiB — only LDS use

    const int tid   = threadIdx.x;
    const int h     = tid & 7;            // owned group (experts 32h..32h+31)
    const int p     = tid >> 3;           // token-in-block
    const int tok0  = blockIdx.x * TPB;
    const int token = tok0 + p;
    const int lane  = tid & 63;
    const int base  = lane & 56;          // first lane of this token's octet

    // ---- issue own-group loads early: one 128B line/thread, 8x b128 ----
    const float4* lg4 = (const float4*)logits;
    float4 st[8];
    #pragma unroll
    for (int k = 0; k < 8; ++k)
        st[k] = lg4[(size_t)token * 64 + h * 8 + k];

    bias_sh[tid] = bias[tid];             // THREADS == NEXP
    __syncthreads();                      // only barrier

    const float4* bias4 = (const float4*)bias_sh;

    // ---------------- pass 1: corrected scores in-place + own-group top-2 ----------------
    float g1 = -3e38f, g2 = -3e38f;       // group top-2 values (ids not needed)
    #pragma unroll
    for (int q = 0; q < 8; ++q) {
        float4 bb = bias4[h * 8 + q];     // broadcast across octets: free
        float4 c;
        c.x = fsigmoid(st[q].x) + bb.x;
        c.y = fsigmoid(st[q].y) + bb.y;
        c.z = fsigmoid(st[q].z) + bb.z;
        c.w = fsigmoid(st[q].w) + bb.w;
        st[q] = c;                        // overwrite logits with scores
        float h1 = fmaxf(c.x, c.y), l1 = fminf(c.x, c.y);
        float h2 = fmaxf(c.z, c.w), l2 = fminf(c.z, c.w);
        float t1 = fmaxf(h1, h2);
        float t2 = fmaxf(fminf(h1, h2), fmaxf(l1, l2));   // top-2 of the quad
        g2 = fmaxf(fminf(g1, t1), fmaxf(g2, t2));         // merge sorted pairs
        g1 = fmaxf(g1, t1);
    }
    float gs = g1 + g2;                   // group score = top-2 sum

    // ---------------- all 8 group scores via bpermute gather ----------------
    float gsv[8];
    #pragma unroll
    for (int g = 0; g < 8; ++g) gsv[g] = __shfl(gs, base + g, 64);

    // ---------------- top-4 groups (rank count, lower idx wins) + margin ----------------
    int selmask = 0; float val4 = 0.f, val5 = 0.f;
    #pragma unroll
    for (int a = 0; a < 8; ++a) {
        int rk = 0;
        #pragma unroll
        for (int b = 0; b < 8; ++b) {
            if (b == a) continue;
            bool beat = (b < a) ? (gsv[b] >= gsv[a]) : (gsv[b] > gsv[a]);
            rk += beat ? 1 : 0;
        }
        selmask |= (rk < 4) ? (1 << a) : 0;
        val4 = (rk == 3) ? gsv[a] : val4;
        val5 = (rk == 4) ? gsv[a] : val5;
    }

    // ---- flagA: ambiguous 4th vs 5th group -> pure-f64 re-rank (cold; logits from global) ----
    if (__builtin_expect(val4 - val5 < EPS_G, 0)) {
        // each thread: own group's f64 top-2 sum (uniform condition per octet)
        double a1 = -1e300, a2 = -1e300;
        const float* lgp = logits + (size_t)token * 256 + h * 32;
        #pragma unroll 1
        for (int k = 0; k < 32; ++k) {
            double c = dsigmoid(lgp[k]) + (double)bias_sh[h * 32 + k];
            a2 = fmax(a2, fmin(a1, c)); a1 = fmax(a1, c);
        }
        double gdo = a1 + a2;
        double gd[8];
        #pragma unroll
        for (int g = 0; g < 8; ++g) gd[g] = __shfl(gdo, base + g, 64);
        int sm = 0;
        #pragma unroll
        for (int a = 0; a < 8; ++a) {
            int rk = 0;
            #pragma unroll
            for (int b = 0; b < 8; ++b) {
                if (b == a) continue;
                bool beat = (b < a) ? (gd[b] >= gd[a]) : (gd[b] > gd[a]);
                rk += beat ? 1 : 0;
            }
            sm |= (rk < 4) ? (1 << a) : 0;
        }
        selmask = sm;
    }

    // ---------------- map thread -> (selected group, half) ----------------
    const int want = h >> 1;              // 0..3 : which selected group (ascending)
    int g = 0, cnt = 0;
    #pragma unroll
    for (int a = 0; a < 8; ++a) {
        bool s = (selmask >> a) & 1;
        g = (s && (cnt == want)) ? a : g;
        cnt += s ? 1 : 0;
    }
    const int hf  = h & 1;                // which 16-element half of the group
    const int src = base + g;             // lane holding that group's scores

    // ---- gather 16 scores via shfl (both halves; static reg indices; convergent) ----
    float4 ga[4];
    #pragma unroll
    for (int j = 0; j < 4; ++j) {
        float4 t0 = shfl4(st[j],     src);
        float4 t1 = shfl4(st[j + 4], src);
        ga[j] = hf ? t1 : t0;
    }

    // ---------------- pass 2: top-9 of my 16 (ids ascending -> exact tie-break) ----------------
    float m0=-3e38f,m1=-3e38f,m2=-3e38f,m3=-3e38f,m4=-3e38f,
          m5=-3e38f,m6=-3e38f,m7=-3e38f,m8=-3e38f;
    int n0=0,n1=0,n2=0,n3=0,n4=0,n5=0,n6=0,n7=0,n8=0;
    const int ebase = g * 32 + hf * 16;
    #pragma unroll
    for (int j = 0; j < 4; ++j) {
        int eb = ebase + j * 4;
        MINS(ga[j].x, eb+0); MINS(ga[j].y, eb+1);
        MINS(ga[j].z, eb+2); MINS(ga[j].w, eb+3);
    }

    // ---------------- butterfly bitonic merges: 8 lists of 9 -> global top-9 ----------------
    XMERGE_B(1);   // halves of same group
    XMERGE_B(2);   // group pairs
    XMERGE_B(4);   // all four groups

    // ---------------- fast-path result + flagB (h==0 lanes own the token) ----------------
    float w0 = m0 - bias_sh[n0], w1 = m1 - bias_sh[n1], w2 = m2 - bias_sh[n2],
          w3 = m3 - bias_sh[n3], w4 = m4 - bias_sh[n4], w5 = m5 - bias_sh[n5],
          w6 = m6 - bias_sh[n6], w7 = m7 - bias_sh[n7];
    int o0=n0,o1=n1,o2=n2,o3=n3,o4=n4,o5=n5,o6=n6,o7=n7;

    bool flagB = (h == 0) &&
                 (((m0-m1)<EPS_S)|((m1-m2)<EPS_S)|((m2-m3)<EPS_S)|((m3-m4)<EPS_S)|
                  ((m4-m5)<EPS_S)|((m5-m6)<EPS_S)|((m6-m7)<EPS_S)|((m7-m8)<EPS_S));
    if (__builtin_expect(flagB, 0)) {
        // f64 re-resolve of the 9 f32-top candidates; logits re-read from global (cold)
        double s0=-1e300,s1=-1e300,s2=-1e300,s3=-1e300,
               s4=-1e300,s5=-1e300,s6=-1e300,s7=-1e300;
        int c0=0,c1=0,c2=0,c3=0,c4=0,c5=0,c6=0,c7=0;
        int ci[9] = {n0,n1,n2,n3,n4,n5,n6,n7,n8};
        const float* lgt = logits + (size_t)token * 256;
        #pragma unroll 1
        for (int k = 0; k < 9; ++k) {
            int e = ci[k];
            double cs = dsigmoid(lgt[e]) + (double)bias_sh[e];
            DINS(cs, e);
        }
        w0=(float)(s0-(double)bias_sh[c0]); o0=c0;
        w1=(float)(s1-(double)bias_sh[c1]); o1=c1;
        w2=(float)(s2-(double)bias_sh[c2]); o2=c2;
        w3=(float)(s3-(double)bias_sh[c3]); o3=c3;
        w4=(float)(s4-(double)bias_sh[c4]); o4=c4;
        w5=(float)(s5-(double)bias_sh[c5]); o5=c5;
        w6=(float)(s6-(double)bias_sh[c6]); o6=c6;
        w7=(float)(s7-(double)bias_sh[c7]); o7=c7;
    }

    // ---------------- epilogue ----------------
    if (h == 0) {
        float sum = ((w0+w1)+(w2+w3)) + ((w4+w5)+(w6+w7));
        float scl = 2.5f / (sum + 1e-20f);
        float4 oa, ob;
        oa.x=w0*scl; oa.y=w1*scl; oa.z=w2*scl; oa.w=w3*scl;
        ob.x=w4*scl; ob.y=w5*scl; ob.z=w6*scl; ob.w=w7*scl;
        *(float4*)(out + (size_t)token*8)     = oa;
        *(float4*)(out + (size_t)token*8 + 4) = ob;
        float* oid = out + (size_t)T*8;
        float4 ia, ib;
        ia.x=(float)o0; ia.y=(float)o1; ia.z=(float)o2; ia.w=(float)o3;
        ib.x=(float)o4; ib.y=(float)o5; ib.z=(float)o6; ib.w=(float)o7;
        *(float4*)(oid + (size_t)token*8)     = ia;
        *(float4*)(oid + (size_t)token*8 + 4) = ib;
    }
}

extern "C" void kernel_launch(void* const* d_in, const int* in_sizes, int n_in,
                              void* d_out, int out_size, void* d_ws, size_t ws_size,
                              hipStream_t stream) {
    const float* logits = (const float*)d_in[0];
    const float* bias   = (const float*)d_in[1];
    float* out = (float*)d_out;
    int T = in_sizes[0] / NEXP;        // 131072
    int nblocks = T / TPB;             // 4096
    noauxtc_router_kernel<<<nblocks, THREADS, 0, stream>>>(logits, bias, out, T);
}